// Round 2
// baseline (258.524 us; speedup 1.0000x reference)
//
#include <hip/hip_runtime.h>
#include <math.h>

// CBAM pillar kernel for MI355X (gfx950) — round 2.
//
// Structure exploited:
//  - unq_inv sorted -> pillar voxels are contiguous runs [start[p], +cnt).
//  - Empty z-bins hold the constant row c0 = relu(b1)@W2 + b2 -> all per-bin
//    reductions collapse to 3 distinct columns (c0, y0, y1).
//  - Weights are pillar-invariant: keep them in registers for the whole
//    grid-stride loop (R1 re-loaded ~90 values + recomputed c0 per pillar).

#define NB   32
#define CIN  5
#define CH   32
#define CO   64

__global__ __launch_bounds__(256) void start_kernel(
    const int* __restrict__ unq_inv, int* __restrict__ start, int n) {
  int i = blockIdx.x * blockDim.x + threadIdx.x;
  if (i >= n) return;
  int p = unq_inv[i];
  if (i == 0 || unq_inv[i - 1] != p) start[p] = i;
}

__global__ __launch_bounds__(256) void cbam_kernel(
    const float* __restrict__ vf, const int* __restrict__ vcoord,
    const int* __restrict__ unq_cnt, const int* __restrict__ start,
    const float* __restrict__ W1, const float* __restrict__ b1,
    const float* __restrict__ W2, const float* __restrict__ b2,
    const float* __restrict__ Wc1, const float* __restrict__ bc1,
    const float* __restrict__ Wc2, const float* __restrict__ bc2,
    const float* __restrict__ Wsp, const float* __restrict__ bsp,
    float* __restrict__ out, int U, int trips, int totalWaves) {
  const int tid  = threadIdx.x;
  const int lane = tid & 63;
  const int wv   = tid >> 6;
  const int wave0 = blockIdx.x * 4 + wv;

  const int j32  = lane & 31;        // h-phase weight row / bin id
  const int half = lane >> 5;        // voxel-in-pair for h; channel-half for chMLP
  const int j16  = lane & 15;        // channel-MLP hidden index
  const int pool = (lane >> 4) & 1;  // 0 = avg pool, 1 = max pool

  // ---- persistent per-lane weight registers (loaded once per wave)
  float w1r[CIN];
#pragma unroll
  for (int i = 0; i < CIN; ++i) w1r[i] = W1[i * CH + j32];
  const float b1r = b1[j32];
  float w2r[CH];
#pragma unroll
  for (int j = 0; j < CH; ++j) w2r[j] = W2[j * CO + lane];
  const float b2r = b2[lane];
  float c0 = b2r;                    // MLP output row for an empty bin
#pragma unroll
  for (int j = 0; j < CH; ++j) c0 += fmaxf(b1[j], 0.0f) * w2r[j];
  float wc1r[CH];
#pragma unroll
  for (int s = 0; s < CH; ++s) wc1r[s] = Wc1[(half * 32 + s) * 16 + j16];
  const float bc1r = bc1[j16];
  float wc2r[16];
#pragma unroll
  for (int j = 0; j < 16; ++j) wc2r[j] = Wc2[j * CO + lane];
  const float bc2r = bc2[lane];
  float wm[7], wx[7];                // wave-uniform -> SGPRs
#pragma unroll
  for (int k = 0; k < 7; ++k) { wm[k] = Wsp[k]; wx[k] = Wsp[7 + k]; }
  const float bspr = bsp[0];

  __shared__ float pooled[4][128];   // wave-private slice; no cross-wave use
  float* pl = pooled[wv];
  float* __restrict__ omask = out + (size_t)U * CO;

  for (int t = 0; t < trips; ++t) {
    int p = wave0 + t * totalWaves;
    if (p >= U) break;               // wave-uniform; no barriers in loop
    p = __builtin_amdgcn_readfirstlane(p);  // force scalar loads below

    const int st   = start[p];
    const int cnt  = unq_cnt[p];
    const bool has2 = (cnt >= 2);
    const int v0 = st;
    const int v1 = has2 ? (st + 1) : st;
    const int bin0 = vcoord[v0 * 4 + 1];
    const int bin1 = vcoord[v1 * 4 + 1];

    // ---- up-dimension MLP for the (<=2) occupied voxels
    const int vh = half ? v1 : v0;   // lanes 0-31: v0, lanes 32-63: v1
    float h = b1r;
#pragma unroll
    for (int i = 0; i < CIN; ++i) h += vf[vh * CIN + i] * w1r[i];
    const float hr = fmaxf(h, 0.0f);
    float y0 = b2r, y1 = b2r;
#pragma unroll
    for (int j = 0; j < CH; ++j) {
      float a = __shfl(hr, j);
      float b = __shfl(hr, 32 + j);
      y0 += a * w2r[j];
      y1 += b * w2r[j];
    }

    // ---- per-channel pooled stats over 32 bins (30 empty bins = c0)
    const float sumy = has2 ? (y0 + y1) : y0;
    const float maxy = has2 ? fmaxf(y0, y1) : y0;
    const int   nocc = has2 ? 2 : 1;
    const float avg  = (c0 * (float)(NB - nocc) + sumy) * (1.0f / (float)NB);
    const float mx   = fmaxf(maxy, c0);

    // ---- channel attention: sigmoid(mlp(avg) + mlp(max))
    // wave-private LDS round trip; within-wave ordering via waitcnt+wave_barrier
    pl[2 * lane]     = avg;
    pl[2 * lane + 1] = mx;
    __builtin_amdgcn_wave_barrier();
    __builtin_amdgcn_s_waitcnt(0xC07F);   // lgkmcnt(0), vmcnt/expcnt ignored
    __builtin_amdgcn_wave_barrier();
    float tt = 0.0f;
#pragma unroll
    for (int s = 0; s < CH; ++s)
      tt += pl[2 * (half * 32 + s) + pool] * wc1r[s];
    tt += __shfl_xor(tt, 32);                   // combine channel halves
    const float r = fmaxf(tt + bc1r, 0.0f);
    const float g = r + __shfl_xor(r, 16);      // relu(h_avg)+relu(h_max)
    float pre = 2.0f * bc2r;
#pragma unroll
    for (int j = 0; j < 16; ++j) pre += __shfl(g, j) * wc2r[j];
    const float attc = 1.0f / (1.0f + __expf(-pre));

    // ---- bin attention: 3 distinct columns -> 3 sum + 3 max butterflies
    const float pc0v = attc * c0;
    const float py0 = attc * y0;
    const float py1 = attc * y1;
    float s_c0 = pc0v, m_c0 = pc0v;
    float s_y0 = py0,  m_y0 = py0;
    float s_y1 = py1,  m_y1 = py1;
#pragma unroll
    for (int d = 1; d < 64; d <<= 1) {
      s_c0 += __shfl_xor(s_c0, d);
      s_y0 += __shfl_xor(s_y0, d);
      s_y1 += __shfl_xor(s_y1, d);
      m_c0 = fmaxf(m_c0, __shfl_xor(m_c0, d));
      m_y0 = fmaxf(m_y0, __shfl_xor(m_y0, d));
      m_y1 = fmaxf(m_y1, __shfl_xor(m_y1, d));
    }
    const float inv64 = 1.0f / 64.0f;
    float mean_b = s_c0 * inv64;
    float max_b  = m_c0;
    if (j32 == bin0)         { mean_b = s_y0 * inv64; max_b = m_y0; }
    if (has2 && j32 == bin1) { mean_b = s_y1 * inv64; max_b = m_y1; }

    // conv1d over bins: kernel 7, zero-pad 3
    float acc = bspr;
#pragma unroll
    for (int k = 0; k < 7; ++k) {
      int idx = j32 + k - 3;
      float mm = __shfl(mean_b, idx & 63);
      float xx = __shfl(max_b, idx & 63);
      float contrib = mm * wm[k] + xx * wx[k];
      acc += (idx >= 0 && idx < NB) ? contrib : 0.0f;
    }
    const float sig = 1.0f / (1.0f + __expf(-acc));

    // extremes of sig over EMPTY bins + sig at occupied bins
    const bool occ = (j32 == bin0) || (has2 && j32 == bin1);
    float sE = occ ? -1e30f : sig;
    float sI = occ ?  1e30f : sig;
#pragma unroll
    for (int d = 1; d < 32; d <<= 1) {
      sE = fmaxf(sE, __shfl_xor(sE, d));
      sI = fminf(sI, __shfl_xor(sI, d));
    }
    const float sig0 = __shfl(sig, bin0);
    const float sig1 = __shfl(sig, bin1);

    // ---- final max over bins of attc * x_b * sig_b  (attc > 0)
    float m = y0 * sig0;
    if (has2) m = fmaxf(m, y1 * sig1);
    const float eterm = (c0 >= 0.0f) ? (c0 * sE) : (c0 * sI);
    m = fmaxf(m, eterm);

    out[(size_t)p * CO + lane] = attc * m;
    if (lane == 0) omask[p] = (cnt >= 2) ? 1.0f : 0.0f;
  }
}

extern "C" void kernel_launch(void* const* d_in, const int* in_sizes, int n_in,
                              void* d_out, int out_size, void* d_ws, size_t ws_size,
                              hipStream_t stream) {
  const float* vf      = (const float*)d_in[0];
  const int*   vcoord  = (const int*)d_in[1];
  // d_in[2] = unq_coords (unused: identity)
  const int*   unq_inv = (const int*)d_in[3];
  const int*   unq_cnt = (const int*)d_in[4];
  const float* W1  = (const float*)d_in[5];
  const float* b1  = (const float*)d_in[6];
  const float* W2  = (const float*)d_in[7];
  const float* b2  = (const float*)d_in[8];
  const float* Wc1 = (const float*)d_in[9];
  const float* bc1 = (const float*)d_in[10];
  const float* Wc2 = (const float*)d_in[11];
  const float* bc2 = (const float*)d_in[12];
  const float* Wsp = (const float*)d_in[13];
  const float* bsp = (const float*)d_in[14];

  const int N = in_sizes[3];   // voxels
  const int U = in_sizes[4];   // pillars

  int* start = (int*)d_ws;     // U ints of scratch

  start_kernel<<<(N + 255) / 256, 256, 0, stream>>>(unq_inv, start, N);

  const int blocks = 2048;               // 8192 waves, grid-stride
  const int totalWaves = blocks * 4;
  const int trips = (U + totalWaves - 1) / totalWaves;
  cbam_kernel<<<blocks, 256, 0, stream>>>(
      vf, vcoord, unq_cnt, start, W1, b1, W2, b2, Wc1, bc1, Wc2, bc2,
      Wsp, bsp, (float*)d_out, U, trips, totalWaves);
}

// Round 4
// 218.463 us; speedup vs baseline: 1.1834x; 1.1834x over previous
//
#include <hip/hip_runtime.h>
#include <math.h>

// CBAM pillar kernel for MI355X (gfx950) — round 4.
//
// R3 bug: the packed half-split reduction dropped half the channels of each
// voxel column (each lane only holds ITS channel's y0/y1).  Fixed with a
// single cross-half exchange before the 5-stage intra-half butterfly.
// Also restored the explicit lgkmcnt wait after LDS writes (as in R2).

#define NB   32
#define CIN  5
#define CH   32
#define CO   64

__global__ __launch_bounds__(256) void start_kernel(
    const int* __restrict__ unq_inv, int* __restrict__ start, int n) {
  int i = blockIdx.x * blockDim.x + threadIdx.x;
  if (i >= n) return;
  int p = unq_inv[i];
  if (i == 0 || unq_inv[i - 1] != p) start[p] = i;
}

__global__ __launch_bounds__(256) void cbam_kernel(
    const float* __restrict__ vf, const int* __restrict__ vcoord,
    const int* __restrict__ unq_cnt, const int* __restrict__ start,
    const float* __restrict__ W1, const float* __restrict__ b1,
    const float* __restrict__ W2, const float* __restrict__ b2,
    const float* __restrict__ Wc1, const float* __restrict__ bc1,
    const float* __restrict__ Wc2, const float* __restrict__ bc2,
    const float* __restrict__ Wsp, const float* __restrict__ bsp,
    float* __restrict__ out, int U, int trips, int totalWaves) {
  const int tid  = threadIdx.x;
  const int lane = tid & 63;
  const int wv   = tid >> 6;
  const int wave0 = blockIdx.x * 4 + wv;

  const int j32  = lane & 31;        // hidden index / bin id
  const int half = lane >> 5;        // voxel-in-pair; channel-half for chMLP
  const int j16  = lane & 15;        // channel-MLP hidden index
  const int pool = (lane >> 4) & 1;  // 0 = avg pool, 1 = max pool

  // ---- persistent per-lane weight registers (loaded once per wave)
  float w1r[CIN];
#pragma unroll
  for (int i = 0; i < CIN; ++i) w1r[i] = W1[i * CH + j32];
  const float b1r = b1[j32];
  float w2r[CH];
#pragma unroll
  for (int j = 0; j < CH; ++j) w2r[j] = W2[j * CO + lane];
  const float b2r = b2[lane];
  float c0 = b2r;                    // MLP output row for an empty bin
#pragma unroll
  for (int j = 0; j < CH; ++j) c0 += fmaxf(b1[j], 0.0f) * w2r[j];
  float wc1r[CH];
#pragma unroll
  for (int s = 0; s < CH; ++s) wc1r[s] = Wc1[(half * 32 + s) * 16 + j16];
  const float bc1r = bc1[j16];
  float wc2r[16];
#pragma unroll
  for (int j = 0; j < 16; ++j) wc2r[j] = Wc2[j * CO + lane];
  const float bc2r = bc2[lane];
  float wm[7], wx[7];                // wave-uniform -> SGPRs
#pragma unroll
  for (int k = 0; k < 7; ++k) { wm[k] = Wsp[k]; wx[k] = Wsp[7 + k]; }
  const float bspr = bsp[0];

  // per-wave LDS slice: [0:64) hr broadcast, [64:64+144) pooled (padded)
  __shared__ __align__(16) float lds[4][224];
  float* const hrb = lds[wv];
  float* const plb = lds[wv] + 64;
  float* __restrict__ omask = out + (size_t)U * CO;

  // ---- prologue: load trip-0 pillar data
  int pcur = wave0 < U ? wave0 : (U - 1);
  int st  = start[pcur];
  int cnt = unq_cnt[pcur];
  int h2  = (cnt >= 2) ? 1 : 0;
  int b0  = vcoord[st * 4 + 1];
  int b1i = vcoord[(st + h2) * 4 + 1];
  float vfr[CIN];
  {
    const int vh = st + (half ? h2 : 0);
#pragma unroll
    for (int i = 0; i < CIN; ++i) vfr[i] = vf[vh * CIN + i];
  }

  for (int t = 0; t < trips; ++t) {
    const int p = wave0 + t * totalWaves;
    if (p >= U) break;               // wave-uniform

    // ---- prefetch next trip's pillar data (hidden under this trip's compute)
    int pn = p + totalWaves;
    pn = pn < U ? pn : (U - 1);
    const int stn  = start[pn];
    const int cntn = unq_cnt[pn];
    const int h2n  = (cntn >= 2) ? 1 : 0;
    const int b0n  = vcoord[stn * 4 + 1];
    const int b1n  = vcoord[(stn + h2n) * 4 + 1];
    float vfn[CIN];
    {
      const int vhn = stn + (half ? h2n : 0);
#pragma unroll
      for (int i = 0; i < CIN; ++i) vfn[i] = vf[vhn * CIN + i];
    }

    const bool has2 = (h2 != 0);

    // ---- up-dimension MLP layer 1 (lanes 0-31: voxel0, 32-63: voxel1)
    float h = b1r;
#pragma unroll
    for (int i = 0; i < CIN; ++i) h += vfr[i] * w1r[i];
    const float hr = fmaxf(h, 0.0f);

    // layer 2 via LDS broadcast: every lane (=channel) uses all 64 hr values
    hrb[lane] = hr;
    __builtin_amdgcn_wave_barrier();
    __builtin_amdgcn_s_waitcnt(0xC07F);   // lgkmcnt(0)
    __builtin_amdgcn_wave_barrier();
    float y0 = b2r, y1 = b2r;
    const float4* h4 = (const float4*)hrb;
#pragma unroll
    for (int k = 0; k < 8; ++k) {
      float4 a = h4[k];       // hr of voxel0, hidden 4k..4k+3 (broadcast)
      float4 b = h4[8 + k];   // hr of voxel1
      y0 += a.x * w2r[4 * k] + a.y * w2r[4 * k + 1] +
            a.z * w2r[4 * k + 2] + a.w * w2r[4 * k + 3];
      y1 += b.x * w2r[4 * k] + b.y * w2r[4 * k + 1] +
            b.z * w2r[4 * k + 2] + b.w * w2r[4 * k + 3];
    }

    // ---- per-channel pooled stats over 32 bins (30 empty bins = c0)
    const float sumy = has2 ? (y0 + y1) : y0;
    const float maxy = has2 ? fmaxf(y0, y1) : y0;
    const float avg  = (c0 * (float)(NB - (has2 ? 2 : 1)) + sumy) *
                       (1.0f / (float)NB);
    const float mx   = fmaxf(maxy, c0);

    // ---- channel attention: sigmoid(mlp(avg) + mlp(max))
    // pooled layout: [pool*72 + half*36 + s] (padded -> conflict-free b128)
    plb[half * 36 + j32]      = avg;
    plb[72 + half * 36 + j32] = mx;
    __builtin_amdgcn_wave_barrier();
    __builtin_amdgcn_s_waitcnt(0xC07F);   // lgkmcnt(0)
    __builtin_amdgcn_wave_barrier();
    float tt = 0.0f;
    const float4* r4 = (const float4*)(plb + pool * 72 + half * 36);
#pragma unroll
    for (int k = 0; k < 8; ++k) {
      float4 q = r4[k];
      tt += q.x * wc1r[4 * k] + q.y * wc1r[4 * k + 1] +
            q.z * wc1r[4 * k + 2] + q.w * wc1r[4 * k + 3];
    }
    tt += __shfl_xor(tt, 32);                   // combine channel halves
    const float r = fmaxf(tt + bc1r, 0.0f);
    const float g = r + __shfl_xor(r, 16);      // relu(h_avg)+relu(h_max)
    float pre = 2.0f * bc2r;
#pragma unroll
    for (int j = 0; j < 16; ++j) pre += __shfl(g, j) * wc2r[j];
    const float attc = 1.0f / (1.0f + __expf(-pre));

    // ---- bin attention reductions (3 distinct columns: c0, y0, y1)
    const float pc0 = attc * c0;
    const float py0 = attc * y0;
    const float py1 = attc * y1;
    // half-split with cross-half exchange:
    //   lane l<32 needs py0[l+32] (held by lane l+32); lane l>=32 needs py1[l-32]
    const float zx = __shfl_xor(half ? py0 : py1, 32);
    float vsum = half ? py1 : py0;
    float vmax = fmaxf(vsum, zx);
    vsum += zx;
#pragma unroll
    for (int d = 1; d < 32; d <<= 1) {   // intra-half butterfly
      vsum += __shfl_xor(vsum, d);
      vmax = fmaxf(vmax, __shfl_xor(vmax, d));
    }
    const float sy0 = __shfl(vsum, 0);   // sum py0 over all 64 channels
    const float sy1 = __shfl(vsum, 32);  // sum py1
    const float my0 = __shfl(vmax, 0);   // max py0
    const float my1 = __shfl(vmax, 32);  // max py1
    // c0 column: full 64-lane reduce (result uniform in-register)
    float sc = pc0, mc = pc0;
#pragma unroll
    for (int d = 1; d < 64; d <<= 1) {
      sc += __shfl_xor(sc, d);
      mc = fmaxf(mc, __shfl_xor(mc, d));
    }

    const float inv64 = 1.0f / 64.0f;
    float mean_b = sc * inv64;           // per-bin mean/max over channels
    float max_b  = mc;                   // (bin = j32; halves identical)
    const bool isb0 = (j32 == b0);
    mean_b = isb0 ? sy0 * inv64 : mean_b;
    max_b  = isb0 ? my0 : max_b;
    const bool isb1 = has2 && (j32 == b1i);
    mean_b = isb1 ? sy1 * inv64 : mean_b;
    max_b  = isb1 ? my1 : max_b;

    // conv1d over bins: kernel 7, zero-pad 3
    float acc = bspr;
#pragma unroll
    for (int k = 0; k < 7; ++k) {
      int idx = j32 + k - 3;
      float mm = __shfl(mean_b, idx & 63);
      float xx = __shfl(max_b, idx & 63);
      acc += (idx >= 0 && idx < NB) ? (mm * wm[k] + xx * wx[k]) : 0.0f;
    }
    const float sig = 1.0f / (1.0f + __expf(-acc));

    // extremes of sig over EMPTY bins (sig identical in both 32-halves)
    const bool occ = isb0 || isb1;
    float sE = occ ? -1e30f : sig;
    float sI = occ ?  1e30f : sig;
#pragma unroll
    for (int d = 1; d < 32; d <<= 1) {
      sE = fmaxf(sE, __shfl_xor(sE, d));
      sI = fminf(sI, __shfl_xor(sI, d));
    }
    const float sig0 = __shfl(sig, b0);
    const float sig1 = __shfl(sig, b1i);

    // ---- final max over bins of attc * x_b * sig_b  (attc > 0)
    float m = y0 * sig0;
    if (has2) m = fmaxf(m, y1 * sig1);
    const float eterm = (c0 >= 0.0f) ? (c0 * sE) : (c0 * sI);
    m = fmaxf(m, eterm);

    out[(size_t)p * CO + lane] = attc * m;
    if (lane == 0) omask[p] = has2 ? 1.0f : 0.0f;

    // ---- rotate pipeline registers
    st = stn; cnt = cntn; h2 = h2n; b0 = b0n; b1i = b1n;
#pragma unroll
    for (int i = 0; i < CIN; ++i) vfr[i] = vfn[i];
  }
}

extern "C" void kernel_launch(void* const* d_in, const int* in_sizes, int n_in,
                              void* d_out, int out_size, void* d_ws, size_t ws_size,
                              hipStream_t stream) {
  const float* vf      = (const float*)d_in[0];
  const int*   vcoord  = (const int*)d_in[1];
  // d_in[2] = unq_coords (unused: identity)
  const int*   unq_inv = (const int*)d_in[3];
  const int*   unq_cnt = (const int*)d_in[4];
  const float* W1  = (const float*)d_in[5];
  const float* b1  = (const float*)d_in[6];
  const float* W2  = (const float*)d_in[7];
  const float* b2  = (const float*)d_in[8];
  const float* Wc1 = (const float*)d_in[9];
  const float* bc1 = (const float*)d_in[10];
  const float* Wc2 = (const float*)d_in[11];
  const float* bc2 = (const float*)d_in[12];
  const float* Wsp = (const float*)d_in[13];
  const float* bsp = (const float*)d_in[14];

  const int N = in_sizes[3];   // voxels
  const int U = in_sizes[4];   // pillars

  int* start = (int*)d_ws;     // U ints of scratch

  start_kernel<<<(N + 255) / 256, 256, 0, stream>>>(unq_inv, start, N);

  const int blocks = 2048;               // 8192 waves, grid-stride
  const int totalWaves = blocks * 4;
  const int trips = (U + totalWaves - 1) / totalWaves;
  cbam_kernel<<<blocks, 256, 0, stream>>>(
      vf, vcoord, unq_cnt, start, W1, b1, W2, b2, Wc1, bc1, Wc2, bc2,
      Wsp, bsp, (float*)d_out, U, trips, totalWaves);
}

// Round 5
// 186.991 us; speedup vs baseline: 1.3825x; 1.1683x over previous
//
#include <hip/hip_runtime.h>
#include <math.h>

// CBAM pillar kernel for MI355X (gfx950) — round 5.
//
// R4 was latency-bound on a ~25-deep ds_bpermute chain (VALUBusy 47%).
// R5: (1) all reductions via DPP (row_shr/row_bcast) on the VALU pipe;
//     (2) bin-attention conv computed analytically from uniform scalars
//         (empty bins share one column) — no per-lane sigmoid, no conv
//         shuffles; (3) broadcasts via v_readlane instead of LDS roundtrip.
// Remaining LDS ops/trip: pooled roundtrip (10), 2 bpermute, 2 table reads.

#define NB   32
#define CIN  5
#define CH   32
#define CO   64

__device__ __forceinline__ float frl(float x, int l) {
  return __builtin_bit_cast(float, __builtin_amdgcn_readlane(
      __builtin_bit_cast(int, x), l));
}
template <int C>
__device__ __forceinline__ float dadd(float s) {  // invalid lanes add 0
  int t = __builtin_amdgcn_update_dpp(0, __builtin_bit_cast(int, s),
                                      C, 0xf, 0xf, true);
  return s + __builtin_bit_cast(float, t);
}
template <int C>
__device__ __forceinline__ float dmax(float m) {  // invalid lanes keep m
  int t = __builtin_amdgcn_update_dpp(__builtin_bit_cast(int, m),
                                      __builtin_bit_cast(int, m),
                                      C, 0xf, 0xf, false);
  return fmaxf(m, __builtin_bit_cast(float, t));
}
// 5-step: lane31 = reduce(lanes 0-31), lane63 = reduce(lanes 32-63)
__device__ __forceinline__ float red32_sum(float s) {
  s = dadd<0x111>(s); s = dadd<0x112>(s); s = dadd<0x114>(s);
  s = dadd<0x118>(s); s = dadd<0x142>(s); return s;
}
__device__ __forceinline__ float red32_max(float m) {
  m = dmax<0x111>(m); m = dmax<0x112>(m); m = dmax<0x114>(m);
  m = dmax<0x118>(m); m = dmax<0x142>(m); return m;
}
__device__ __forceinline__ float red64_sum(float s) {
  return dadd<0x143>(red32_sum(s));   // lane63 = full-wave sum
}
__device__ __forceinline__ float red64_max(float m) {
  return dmax<0x143>(red32_max(m));   // lane63 = full-wave max
}
__device__ __forceinline__ float sgm(float x) {
  return 1.0f / (1.0f + __expf(-x));
}

__global__ __launch_bounds__(256) void start_kernel(
    const int* __restrict__ unq_inv, int* __restrict__ start, int n) {
  int i = blockIdx.x * blockDim.x + threadIdx.x;
  if (i >= n) return;
  int p = unq_inv[i];
  if (i == 0 || unq_inv[i - 1] != p) start[p] = i;
}

__global__ __launch_bounds__(256, 4) void cbam_kernel(
    const float* __restrict__ vf, const int* __restrict__ vcoord,
    const int* __restrict__ unq_cnt, const int* __restrict__ start,
    const float* __restrict__ W1, const float* __restrict__ b1,
    const float* __restrict__ W2, const float* __restrict__ b2,
    const float* __restrict__ Wc1, const float* __restrict__ bc1,
    const float* __restrict__ Wc2, const float* __restrict__ bc2,
    const float* __restrict__ Wsp, const float* __restrict__ bsp,
    float* __restrict__ out, int U, int trips, int totalWaves) {
  const int tid  = threadIdx.x;
  const int lane = tid & 63;
  const int wv   = tid >> 6;
  const int wave0 = blockIdx.x * 4 + wv;

  const int j32  = lane & 31;        // hidden index / bin id
  const int half = lane >> 5;        // voxel-in-pair; channel-half for chMLP
  const int j16  = lane & 15;        // channel-MLP hidden index
  const int pool = (lane >> 4) & 1;  // 0 = avg pool, 1 = max pool

  // ---- persistent per-lane weight registers (loaded once per wave)
  float w1r[CIN];
#pragma unroll
  for (int i = 0; i < CIN; ++i) w1r[i] = W1[i * CH + j32];
  const float b1r = b1[j32];
  float w2r[CH];
#pragma unroll
  for (int j = 0; j < CH; ++j) w2r[j] = W2[j * CO + lane];
  const float b2r = b2[lane];
  float c0 = b2r;                    // MLP output row for an empty bin
#pragma unroll
  for (int j = 0; j < CH; ++j) c0 += fmaxf(b1[j], 0.0f) * w2r[j];
  float wc1r[CH];
#pragma unroll
  for (int s = 0; s < CH; ++s) wc1r[s] = Wc1[(half * 32 + s) * 16 + j16];
  const float bc1r = bc1[j16];
  float wc2r[16];
#pragma unroll
  for (int j = 0; j < 16; ++j) wc2r[j] = Wc2[j * CO + lane];
  const float bc2r = bc2[lane];
  const float bspr = bsp[0];

  // per-lane clipped conv-window weight sums (bin = j32), computed once
  float wsum_m = 0.0f, wsum_x = 0.0f;
#pragma unroll
  for (int k = 0; k < 7; ++k) {
    const bool vld = (unsigned)(j32 + k - 3) < 32u;
    wsum_m += vld ? Wsp[k]     : 0.0f;
    wsum_x += vld ? Wsp[7 + k] : 0.0f;
  }

  // LDS: per-wave pooled buffer (144 floats) + shared conv-weight table
  __shared__ __align__(16) float plds[4][144];
  __shared__ float2 wtab[8];         // {wm[k], wx[k]}, entry 7 = {0,0}
  if (tid < 8) {
    float a = 0.0f, b = 0.0f;
    if (tid < 7) { a = Wsp[tid]; b = Wsp[7 + tid]; }
    wtab[tid] = make_float2(a, b);
  }
  __syncthreads();
  float* const plb = plds[wv];
  float* __restrict__ omask = out + (size_t)U * CO;

  // ---- prologue: load trip-0 pillar data
  int pcur = wave0 < U ? wave0 : (U - 1);
  int st  = start[pcur];
  int cnt = unq_cnt[pcur];
  int h2  = (cnt >= 2) ? 1 : 0;
  int b0  = vcoord[st * 4 + 1];
  int b1i = vcoord[(st + h2) * 4 + 1];
  float vfr[CIN];
  {
    const int vh = st + (half ? h2 : 0);
#pragma unroll
    for (int i = 0; i < CIN; ++i) vfr[i] = vf[vh * CIN + i];
  }

  for (int t = 0; t < trips; ++t) {
    const int p = wave0 + t * totalWaves;
    if (p >= U) break;               // wave-uniform

    // ---- prefetch next trip's pillar data
    int pn = p + totalWaves;
    pn = pn < U ? pn : (U - 1);
    const int stn  = start[pn];
    const int cntn = unq_cnt[pn];
    const int h2n  = (cntn >= 2) ? 1 : 0;
    const int b0n  = vcoord[stn * 4 + 1];
    const int b1n  = vcoord[(stn + h2n) * 4 + 1];
    float vfn[CIN];
    {
      const int vhn = stn + (half ? h2n : 0);
#pragma unroll
      for (int i = 0; i < CIN; ++i) vfn[i] = vf[vhn * CIN + i];
    }

    const bool has2 = (h2 != 0);

    // ---- up-dimension MLP layer 1 (lanes 0-31: voxel0, 32-63: voxel1)
    float h = b1r;
#pragma unroll
    for (int i = 0; i < CIN; ++i) h += vfr[i] * w1r[i];
    const float hr = fmaxf(h, 0.0f);

    // layer 2 via readlane broadcast (VALU; no LDS)
    float y0 = b2r, y1 = b2r;
#pragma unroll
    for (int j = 0; j < CH; ++j) {
      y0 += frl(hr, j) * w2r[j];
      y1 += frl(hr, 32 + j) * w2r[j];
    }

    // ---- per-channel pooled stats over 32 bins (30 empty bins = c0)
    const float sumy = has2 ? (y0 + y1) : y0;
    const float maxy = has2 ? fmaxf(y0, y1) : y0;
    const float avg  = (c0 * (float)(NB - (has2 ? 2 : 1)) + sumy) *
                       (1.0f / (float)NB);
    const float mx   = fmaxf(maxy, c0);

    // ---- channel attention: sigmoid(mlp(avg) + mlp(max))
    // pooled layout: [pool*72 + half*36 + s] (padded -> conflict-free b128)
    plb[half * 36 + j32]      = avg;
    plb[72 + half * 36 + j32] = mx;
    __builtin_amdgcn_wave_barrier();
    __builtin_amdgcn_s_waitcnt(0xC07F);   // lgkmcnt(0)
    __builtin_amdgcn_wave_barrier();
    float tt = 0.0f;
    const float4* r4 = (const float4*)(plb + pool * 72 + half * 36);
#pragma unroll
    for (int k = 0; k < 8; ++k) {
      float4 q = r4[k];
      tt += q.x * wc1r[4 * k] + q.y * wc1r[4 * k + 1] +
            q.z * wc1r[4 * k + 2] + q.w * wc1r[4 * k + 3];
    }
    tt += __shfl_xor(tt, 32);                   // combine channel halves
    const float r = fmaxf(tt + bc1r, 0.0f);
    const float g = r + __shfl_xor(r, 16);      // relu(h_avg)+relu(h_max)
    float pre = 2.0f * bc2r;
#pragma unroll
    for (int j = 0; j < 16; ++j) pre += frl(g, j) * wc2r[j];
    const float attc = sgm(pre);

    // ---- bin-attention reductions via DPP (3 columns: c0, y0, y1)
    const float pc0 = attc * c0;
    const float py0 = attc * y0;
    const float py1 = attc * y1;
    const float aa = half ? py1 : py0;
    const float zx = __shfl_xor(half ? py0 : py1, 32);  // cross-half exch
    float vs = red32_sum(aa + zx);
    float vm = red32_max(fmaxf(aa, zx));
    const float sy0 = frl(vs, 31), sy1 = frl(vs, 63);
    const float my0 = frl(vm, 31), my1 = frl(vm, 63);
    const float sc  = frl(red64_sum(pc0), 63);
    const float mc  = frl(red64_max(pc0), 63);

    // ---- analytic conv: acc_j = bspr + Mn*wsum_m + Mx*wsum_x + corrections
    const float inv64 = 1.0f / 64.0f;
    const float Mn = sc * inv64;
    const float Mx = mc;
    int k0 = b0 - j32 + 3;  k0 = ((unsigned)k0 <= 6u) ? k0 : 7;
    int k1 = b1i - j32 + 3; k1 = (has2 && (unsigned)k1 <= 6u) ? k1 : 7;
    const float2 w0 = wtab[k0];
    const float2 w1c = wtab[k1];
    const float acc = bspr + Mn * wsum_m + Mx * wsum_x +
                      ((sy0 - sc) * inv64) * w0.x + (my0 - mc) * w0.y +
                      ((sy1 - sc) * inv64) * w1c.x + (my1 - mc) * w1c.y;

    // sigmoid only at the 4 points that matter (monotone => reduce acc)
    const bool occ = (j32 == b0) || (has2 && (j32 == b1i));
    const float macc =  frl(red32_max(occ ? -3.0e38f :  acc), 31);
    const float nacc = -frl(red32_max(occ ? -3.0e38f : -acc), 31);
    const float sig0 = sgm(frl(acc, b0));
    const float sig1 = sgm(frl(acc, b1i));
    const float sE = sgm(macc);   // max sigmoid over empty bins
    const float sI = sgm(nacc);   // min sigmoid over empty bins

    // ---- final max over bins of attc * x_b * sig_b  (attc > 0)
    float m = y0 * sig0;
    if (has2) m = fmaxf(m, y1 * sig1);
    const float eterm = (c0 >= 0.0f) ? (c0 * sE) : (c0 * sI);
    m = fmaxf(m, eterm);

    out[(size_t)p * CO + lane] = attc * m;
    if (lane == 0) omask[p] = has2 ? 1.0f : 0.0f;

    // ---- rotate pipeline registers
    st = stn; cnt = cntn; h2 = h2n; b0 = b0n; b1i = b1n;
#pragma unroll
    for (int i = 0; i < CIN; ++i) vfr[i] = vfn[i];
  }
}

extern "C" void kernel_launch(void* const* d_in, const int* in_sizes, int n_in,
                              void* d_out, int out_size, void* d_ws, size_t ws_size,
                              hipStream_t stream) {
  const float* vf      = (const float*)d_in[0];
  const int*   vcoord  = (const int*)d_in[1];
  // d_in[2] = unq_coords (unused: identity)
  const int*   unq_inv = (const int*)d_in[3];
  const int*   unq_cnt = (const int*)d_in[4];
  const float* W1  = (const float*)d_in[5];
  const float* b1  = (const float*)d_in[6];
  const float* W2  = (const float*)d_in[7];
  const float* b2  = (const float*)d_in[8];
  const float* Wc1 = (const float*)d_in[9];
  const float* bc1 = (const float*)d_in[10];
  const float* Wc2 = (const float*)d_in[11];
  const float* bc2 = (const float*)d_in[12];
  const float* Wsp = (const float*)d_in[13];
  const float* bsp = (const float*)d_in[14];

  const int N = in_sizes[3];   // voxels
  const int U = in_sizes[4];   // pillars

  int* start = (int*)d_ws;     // U ints of scratch

  start_kernel<<<(N + 255) / 256, 256, 0, stream>>>(unq_inv, start, N);

  const int blocks = 2048;               // 8192 waves, grid-stride
  const int totalWaves = blocks * 4;
  const int trips = (U + totalWaves - 1) / totalWaves;
  cbam_kernel<<<blocks, 256, 0, stream>>>(
      vf, vcoord, unq_cnt, start, W1, b1, W2, b2, Wc1, bc1, Wc2, bc2,
      Wsp, bsp, (float*)d_out, U, trips, totalWaves);
}

// Round 6
// 177.739 us; speedup vs baseline: 1.4545x; 1.0521x over previous
//
#include <hip/hip_runtime.h>
#include <math.h>

// CBAM pillar kernel for MI355X (gfx950) — round 6.
//
// R5 postmortem: __launch_bounds__(256,4) capped VGPRs at 64 -> scratch
// spills (FETCH/WRITE grew ~14MB; 40ms outlier dispatch).  Also 64
// v_readlane+FMA pairs loaded the VALU pipe while LDS sat idle.
// R6: no launch-bounds cap (no spills); layer-2 broadcast via LDS float4
// (R4-proven); 2-way split accumulators.  Keeps R5's DPP reductions,
// analytic conv (no per-lane sigmoid), 4-sigmoid monotonicity trick.

#define NB   32
#define CIN  5
#define CH   32
#define CO   64

__device__ __forceinline__ float frl(float x, int l) {
  return __builtin_bit_cast(float, __builtin_amdgcn_readlane(
      __builtin_bit_cast(int, x), l));
}
template <int C>
__device__ __forceinline__ float dadd(float s) {  // invalid lanes add 0
  int t = __builtin_amdgcn_update_dpp(0, __builtin_bit_cast(int, s),
                                      C, 0xf, 0xf, true);
  return s + __builtin_bit_cast(float, t);
}
template <int C>
__device__ __forceinline__ float dmax(float m) {  // invalid lanes keep m
  int t = __builtin_amdgcn_update_dpp(__builtin_bit_cast(int, m),
                                      __builtin_bit_cast(int, m),
                                      C, 0xf, 0xf, false);
  return fmaxf(m, __builtin_bit_cast(float, t));
}
// 5-step: lane31 = reduce(lanes 0-31), lane63 = reduce(lanes 32-63)
__device__ __forceinline__ float red32_sum(float s) {
  s = dadd<0x111>(s); s = dadd<0x112>(s); s = dadd<0x114>(s);
  s = dadd<0x118>(s); s = dadd<0x142>(s); return s;
}
__device__ __forceinline__ float red32_max(float m) {
  m = dmax<0x111>(m); m = dmax<0x112>(m); m = dmax<0x114>(m);
  m = dmax<0x118>(m); m = dmax<0x142>(m); return m;
}
__device__ __forceinline__ float red64_sum(float s) {
  return dadd<0x143>(red32_sum(s));   // lane63 = full-wave sum
}
__device__ __forceinline__ float red64_max(float m) {
  return dmax<0x143>(red32_max(m));   // lane63 = full-wave max
}
__device__ __forceinline__ float sgm(float x) {
  return 1.0f / (1.0f + __expf(-x));
}

__global__ __launch_bounds__(256) void start_kernel(
    const int* __restrict__ unq_inv, int* __restrict__ start, int n) {
  int i = blockIdx.x * blockDim.x + threadIdx.x;
  if (i >= n) return;
  int p = unq_inv[i];
  if (i == 0 || unq_inv[i - 1] != p) start[p] = i;
}

__global__ __launch_bounds__(256) void cbam_kernel(
    const float* __restrict__ vf, const int* __restrict__ vcoord,
    const int* __restrict__ unq_cnt, const int* __restrict__ start,
    const float* __restrict__ W1, const float* __restrict__ b1,
    const float* __restrict__ W2, const float* __restrict__ b2,
    const float* __restrict__ Wc1, const float* __restrict__ bc1,
    const float* __restrict__ Wc2, const float* __restrict__ bc2,
    const float* __restrict__ Wsp, const float* __restrict__ bsp,
    float* __restrict__ out, int U, int trips, int totalWaves) {
  const int tid  = threadIdx.x;
  const int lane = tid & 63;
  const int wv   = tid >> 6;
  const int wave0 = blockIdx.x * 4 + wv;

  const int j32  = lane & 31;        // hidden index / bin id
  const int half = lane >> 5;        // voxel-in-pair; channel-half for chMLP
  const int j16  = lane & 15;        // channel-MLP hidden index
  const int pool = (lane >> 4) & 1;  // 0 = avg pool, 1 = max pool

  // ---- persistent per-lane weight registers (loaded once per wave)
  float w1r[CIN];
#pragma unroll
  for (int i = 0; i < CIN; ++i) w1r[i] = W1[i * CH + j32];
  const float b1r = b1[j32];
  float w2r[CH];
#pragma unroll
  for (int j = 0; j < CH; ++j) w2r[j] = W2[j * CO + lane];
  const float b2r = b2[lane];
  float c0 = b2r;                    // MLP output row for an empty bin
#pragma unroll
  for (int j = 0; j < CH; ++j) c0 += fmaxf(b1[j], 0.0f) * w2r[j];
  float wc1r[CH];
#pragma unroll
  for (int s = 0; s < CH; ++s) wc1r[s] = Wc1[(half * 32 + s) * 16 + j16];
  const float bc1r = bc1[j16];
  float wc2r[16];
#pragma unroll
  for (int j = 0; j < 16; ++j) wc2r[j] = Wc2[j * CO + lane];
  const float bc2r = bc2[lane];
  const float bspr = bsp[0];

  // per-lane clipped conv-window weight sums (bin = j32), computed once
  float wsum_m = 0.0f, wsum_x = 0.0f;
#pragma unroll
  for (int k = 0; k < 7; ++k) {
    const bool vld = (unsigned)(j32 + k - 3) < 32u;
    wsum_m += vld ? Wsp[k]     : 0.0f;
    wsum_x += vld ? Wsp[7 + k] : 0.0f;
  }

  // per-wave LDS slice: [0:64) hr broadcast, [64:208) pooled (padded)
  __shared__ __align__(16) float lds[4][224];
  __shared__ float2 wtab[8];         // {wm[k], wx[k]}, entry 7 = {0,0}
  if (tid < 8) {
    float a = 0.0f, b = 0.0f;
    if (tid < 7) { a = Wsp[tid]; b = Wsp[7 + tid]; }
    wtab[tid] = make_float2(a, b);
  }
  __syncthreads();
  float* const hrb = lds[wv];
  float* const plb = lds[wv] + 64;
  float* __restrict__ omask = out + (size_t)U * CO;

  // ---- prologue: load trip-0 pillar data
  int pcur = wave0 < U ? wave0 : (U - 1);
  int st  = start[pcur];
  int cnt = unq_cnt[pcur];
  int h2  = (cnt >= 2) ? 1 : 0;
  int b0  = vcoord[st * 4 + 1];
  int b1i = vcoord[(st + h2) * 4 + 1];
  float vfr[CIN];
  {
    const int vh = st + (half ? h2 : 0);
#pragma unroll
    for (int i = 0; i < CIN; ++i) vfr[i] = vf[vh * CIN + i];
  }

  for (int t = 0; t < trips; ++t) {
    const int p = wave0 + t * totalWaves;
    if (p >= U) break;               // wave-uniform

    // ---- prefetch next trip's pillar data
    int pn = p + totalWaves;
    pn = pn < U ? pn : (U - 1);
    const int stn  = start[pn];
    const int cntn = unq_cnt[pn];
    const int h2n  = (cntn >= 2) ? 1 : 0;
    const int b0n  = vcoord[stn * 4 + 1];
    const int b1n  = vcoord[(stn + h2n) * 4 + 1];
    float vfn[CIN];
    {
      const int vhn = stn + (half ? h2n : 0);
#pragma unroll
      for (int i = 0; i < CIN; ++i) vfn[i] = vf[vhn * CIN + i];
    }

    const bool has2 = (h2 != 0);

    // ---- up-dimension MLP layer 1 (lanes 0-31: voxel0, 32-63: voxel1)
    float h = b1r;
#pragma unroll
    for (int i = 0; i < CIN; ++i) h += vfr[i] * w1r[i];
    const float hr = fmaxf(h, 0.0f);

    // layer 2 via LDS broadcast reads (off the VALU pipe), 2-way split acc
    hrb[lane] = hr;
    __builtin_amdgcn_wave_barrier();
    __builtin_amdgcn_s_waitcnt(0xC07F);   // lgkmcnt(0)
    __builtin_amdgcn_wave_barrier();
    const float4* h4 = (const float4*)hrb;
    float y0a = b2r, y0b = 0.0f, y1a = b2r, y1b = 0.0f;
#pragma unroll
    for (int k = 0; k < 4; ++k) {
      float4 a = h4[k];        // voxel0 hr, hidden 4k..4k+3 (broadcast)
      float4 b = h4[4 + k];    // voxel0 hr, hidden 16+4k..
      float4 c = h4[8 + k];    // voxel1 hr
      float4 d = h4[12 + k];
      y0a += a.x * w2r[4 * k]      + a.y * w2r[4 * k + 1] +
             a.z * w2r[4 * k + 2]  + a.w * w2r[4 * k + 3];
      y0b += b.x * w2r[16 + 4 * k]     + b.y * w2r[16 + 4 * k + 1] +
             b.z * w2r[16 + 4 * k + 2] + b.w * w2r[16 + 4 * k + 3];
      y1a += c.x * w2r[4 * k]      + c.y * w2r[4 * k + 1] +
             c.z * w2r[4 * k + 2]  + c.w * w2r[4 * k + 3];
      y1b += d.x * w2r[16 + 4 * k]     + d.y * w2r[16 + 4 * k + 1] +
             d.z * w2r[16 + 4 * k + 2] + d.w * w2r[16 + 4 * k + 3];
    }
    const float y0 = y0a + y0b;
    const float y1 = y1a + y1b;

    // ---- per-channel pooled stats over 32 bins (30 empty bins = c0)
    const float sumy = has2 ? (y0 + y1) : y0;
    const float maxy = has2 ? fmaxf(y0, y1) : y0;
    const float avg  = (c0 * (float)(NB - (has2 ? 2 : 1)) + sumy) *
                       (1.0f / (float)NB);
    const float mx   = fmaxf(maxy, c0);

    // ---- channel attention: sigmoid(mlp(avg) + mlp(max))
    // pooled layout: [pool*72 + half*36 + s] (padded -> conflict-free b128)
    plb[half * 36 + j32]      = avg;
    plb[72 + half * 36 + j32] = mx;
    __builtin_amdgcn_wave_barrier();
    __builtin_amdgcn_s_waitcnt(0xC07F);   // lgkmcnt(0)
    __builtin_amdgcn_wave_barrier();
    float ta = 0.0f, tb = 0.0f;
    const float4* r4 = (const float4*)(plb + pool * 72 + half * 36);
#pragma unroll
    for (int k = 0; k < 4; ++k) {
      float4 q = r4[k];
      float4 u = r4[4 + k];
      ta += q.x * wc1r[4 * k]      + q.y * wc1r[4 * k + 1] +
            q.z * wc1r[4 * k + 2]  + q.w * wc1r[4 * k + 3];
      tb += u.x * wc1r[16 + 4 * k]     + u.y * wc1r[16 + 4 * k + 1] +
            u.z * wc1r[16 + 4 * k + 2] + u.w * wc1r[16 + 4 * k + 3];
    }
    float tt = ta + tb;
    tt += __shfl_xor(tt, 32);                   // combine channel halves
    const float r = fmaxf(tt + bc1r, 0.0f);
    const float g = r + __shfl_xor(r, 16);      // relu(h_avg)+relu(h_max)
    float pre = 2.0f * bc2r;
#pragma unroll
    for (int j = 0; j < 16; ++j) pre += frl(g, j) * wc2r[j];
    const float attc = sgm(pre);

    // ---- bin-attention reductions via DPP (3 columns: c0, y0, y1)
    const float pc0 = attc * c0;
    const float py0 = attc * y0;
    const float py1 = attc * y1;
    const float aa = half ? py1 : py0;
    const float zx = __shfl_xor(half ? py0 : py1, 32);  // cross-half exch
    float vs = red32_sum(aa + zx);
    float vm = red32_max(fmaxf(aa, zx));
    const float sy0 = frl(vs, 31), sy1 = frl(vs, 63);
    const float my0 = frl(vm, 31), my1 = frl(vm, 63);
    const float sc  = frl(red64_sum(pc0), 63);
    const float mc  = frl(red64_max(pc0), 63);

    // ---- analytic conv: acc_j = bspr + Mn*wsum_m + Mx*wsum_x + corrections
    const float inv64 = 1.0f / 64.0f;
    const float Mn = sc * inv64;
    const float Mx = mc;
    int k0 = b0 - j32 + 3;  k0 = ((unsigned)k0 <= 6u) ? k0 : 7;
    int k1 = b1i - j32 + 3; k1 = (has2 && (unsigned)k1 <= 6u) ? k1 : 7;
    const float2 w0 = wtab[k0];
    const float2 w1c = wtab[k1];
    const float acc = bspr + Mn * wsum_m + Mx * wsum_x +
                      ((sy0 - sc) * inv64) * w0.x + (my0 - mc) * w0.y +
                      ((sy1 - sc) * inv64) * w1c.x + (my1 - mc) * w1c.y;

    // sigmoid only at the 4 points that matter (monotone => reduce acc)
    const bool occ = (j32 == b0) || (has2 && (j32 == b1i));
    const float macc =  frl(red32_max(occ ? -3.0e38f :  acc), 31);
    const float nacc = -frl(red32_max(occ ? -3.0e38f : -acc), 31);
    const float sig0 = sgm(frl(acc, b0));
    const float sig1 = sgm(frl(acc, b1i));
    const float sE = sgm(macc);   // max sigmoid over empty bins
    const float sI = sgm(nacc);   // min sigmoid over empty bins

    // ---- final max over bins of attc * x_b * sig_b  (attc > 0)
    float m = y0 * sig0;
    if (has2) m = fmaxf(m, y1 * sig1);
    const float eterm = (c0 >= 0.0f) ? (c0 * sE) : (c0 * sI);
    m = fmaxf(m, eterm);

    out[(size_t)p * CO + lane] = attc * m;
    if (lane == 0) omask[p] = has2 ? 1.0f : 0.0f;

    // ---- rotate pipeline registers
    st = stn; cnt = cntn; h2 = h2n; b0 = b0n; b1i = b1n;
#pragma unroll
    for (int i = 0; i < CIN; ++i) vfr[i] = vfn[i];
  }
}

extern "C" void kernel_launch(void* const* d_in, const int* in_sizes, int n_in,
                              void* d_out, int out_size, void* d_ws, size_t ws_size,
                              hipStream_t stream) {
  const float* vf      = (const float*)d_in[0];
  const int*   vcoord  = (const int*)d_in[1];
  // d_in[2] = unq_coords (unused: identity)
  const int*   unq_inv = (const int*)d_in[3];
  const int*   unq_cnt = (const int*)d_in[4];
  const float* W1  = (const float*)d_in[5];
  const float* b1  = (const float*)d_in[6];
  const float* W2  = (const float*)d_in[7];
  const float* b2  = (const float*)d_in[8];
  const float* Wc1 = (const float*)d_in[9];
  const float* bc1 = (const float*)d_in[10];
  const float* Wc2 = (const float*)d_in[11];
  const float* bc2 = (const float*)d_in[12];
  const float* Wsp = (const float*)d_in[13];
  const float* bsp = (const float*)d_in[14];

  const int N = in_sizes[3];   // voxels
  const int U = in_sizes[4];   // pillars

  int* start = (int*)d_ws;     // U ints of scratch

  start_kernel<<<(N + 255) / 256, 256, 0, stream>>>(unq_inv, start, N);

  const int blocks = 2048;               // 8192 waves, grid-stride
  const int totalWaves = blocks * 4;
  const int trips = (U + totalWaves - 1) / totalWaves;
  cbam_kernel<<<blocks, 256, 0, stream>>>(
      vf, vcoord, unq_cnt, start, W1, b1, W2, b2, Wc1, bc1, Wc2, bc2,
      Wsp, bsp, (float*)d_out, U, trips, totalWaves);
}

// Round 7
// 170.720 us; speedup vs baseline: 1.5143x; 1.0411x over previous
//
#include <hip/hip_runtime.h>
#include <math.h>

// CBAM pillar kernel for MI355X (gfx950) — round 7.
//
// R6 evidence: removing 128 VALU instr/trip changed nothing -> not issue
// bound; the per-trip cost (~2600cy/SIMD-trip) is the serial dependent
// load chain start[p] -> vcoord/vf (2 L2/L3 round trips) that ~2 waves/SIMD
// cannot hide.  R7: pack_kernel materializes per-pillar records
// {vf0[5], vf1[5], b0, b1} (48B) so the trip prefetch is 3 INDEPENDENT
// dwordx4 loads + cnt, pipelined 1 trip ahead in the vmcnt domain
// (separate from the LDS lgkmcnt drains).  Also: 4-way split of the
// serial readlane 'pre' chain; 2-way conv accumulation split.

#define NB   32
#define CIN  5
#define CH   32
#define CO   64

__device__ __forceinline__ float frl(float x, int l) {
  return __builtin_bit_cast(float, __builtin_amdgcn_readlane(
      __builtin_bit_cast(int, x), l));
}
template <int C>
__device__ __forceinline__ float dadd(float s) {  // invalid lanes add 0
  int t = __builtin_amdgcn_update_dpp(0, __builtin_bit_cast(int, s),
                                      C, 0xf, 0xf, true);
  return s + __builtin_bit_cast(float, t);
}
template <int C>
__device__ __forceinline__ float dmax(float m) {  // invalid lanes keep m
  int t = __builtin_amdgcn_update_dpp(__builtin_bit_cast(int, m),
                                      __builtin_bit_cast(int, m),
                                      C, 0xf, 0xf, false);
  return fmaxf(m, __builtin_bit_cast(float, t));
}
// 5-step: lane31 = reduce(lanes 0-31), lane63 = reduce(lanes 32-63)
__device__ __forceinline__ float red32_sum(float s) {
  s = dadd<0x111>(s); s = dadd<0x112>(s); s = dadd<0x114>(s);
  s = dadd<0x118>(s); s = dadd<0x142>(s); return s;
}
__device__ __forceinline__ float red32_max(float m) {
  m = dmax<0x111>(m); m = dmax<0x112>(m); m = dmax<0x114>(m);
  m = dmax<0x118>(m); m = dmax<0x142>(m); return m;
}
__device__ __forceinline__ float red64_sum(float s) {
  return dadd<0x143>(red32_sum(s));   // lane63 = full-wave sum
}
__device__ __forceinline__ float red64_max(float m) {
  return dmax<0x143>(red32_max(m));   // lane63 = full-wave max
}
__device__ __forceinline__ float sgm(float x) {
  return 1.0f / (1.0f + __expf(-x));
}

// per-voxel: build packed pillar record pd[p] = {vf0[5], vf1[5], b0, b1}
__global__ __launch_bounds__(256) void pack_kernel(
    const float* __restrict__ vf, const int* __restrict__ vcoord,
    const int* __restrict__ unq_inv, float* __restrict__ pd, int n) {
  int i = blockIdx.x * blockDim.x + threadIdx.x;
  if (i >= n) return;
  int p = unq_inv[i];
  int slot = (i > 0 && unq_inv[i - 1] == p) ? 1 : 0;
  float* dst = pd + 12 * (size_t)p;
#pragma unroll
  for (int k = 0; k < 5; ++k) dst[5 * slot + k] = vf[5 * i + k];
  ((int*)dst)[10 + slot] = vcoord[4 * i + 1];
}

__global__ __launch_bounds__(256) void cbam_kernel(
    const float* __restrict__ pd, const int* __restrict__ unq_cnt,
    const float* __restrict__ W1, const float* __restrict__ b1,
    const float* __restrict__ W2, const float* __restrict__ b2,
    const float* __restrict__ Wc1, const float* __restrict__ bc1,
    const float* __restrict__ Wc2, const float* __restrict__ bc2,
    const float* __restrict__ Wsp, const float* __restrict__ bsp,
    float* __restrict__ out, int U, int trips, int totalWaves) {
  const int tid  = threadIdx.x;
  const int lane = tid & 63;
  const int wv   = tid >> 6;
  const int wave0 = blockIdx.x * 4 + wv;

  const int j32  = lane & 31;        // hidden index / bin id
  const int half = lane >> 5;        // voxel-in-pair; channel-half for chMLP
  const int j16  = lane & 15;        // channel-MLP hidden index
  const int pool = (lane >> 4) & 1;  // 0 = avg pool, 1 = max pool

  // ---- persistent per-lane weight registers (loaded once per wave)
  float w1r[CIN];
#pragma unroll
  for (int i = 0; i < CIN; ++i) w1r[i] = W1[i * CH + j32];
  const float b1r = b1[j32];
  float w2r[CH];
#pragma unroll
  for (int j = 0; j < CH; ++j) w2r[j] = W2[j * CO + lane];
  const float b2r = b2[lane];
  float c0 = b2r;                    // MLP output row for an empty bin
#pragma unroll
  for (int j = 0; j < CH; ++j) c0 += fmaxf(b1[j], 0.0f) * w2r[j];
  float wc1r[CH];
#pragma unroll
  for (int s = 0; s < CH; ++s) wc1r[s] = Wc1[(half * 32 + s) * 16 + j16];
  const float bc1r = bc1[j16];
  float wc2r[16];
#pragma unroll
  for (int j = 0; j < 16; ++j) wc2r[j] = Wc2[j * CO + lane];
  const float bc2r = bc2[lane];
  const float bspr = bsp[0];

  // per-lane clipped conv-window weight sums (bin = j32), computed once
  float wsum_m = 0.0f, wsum_x = 0.0f;
#pragma unroll
  for (int k = 0; k < 7; ++k) {
    const bool vld = (unsigned)(j32 + k - 3) < 32u;
    wsum_m += vld ? Wsp[k]     : 0.0f;
    wsum_x += vld ? Wsp[7 + k] : 0.0f;
  }

  // per-wave LDS slice: [0:64) hr broadcast, [64:208) pooled (padded)
  __shared__ __align__(16) float lds[4][224];
  __shared__ float2 wtab[8];         // {wm[k], wx[k]}, entry 7 = {0,0}
  if (tid < 8) {
    float a = 0.0f, b = 0.0f;
    if (tid < 7) { a = Wsp[tid]; b = Wsp[7 + tid]; }
    wtab[tid] = make_float2(a, b);
  }
  __syncthreads();
  float* const hrb = lds[wv];
  float* const plb = lds[wv] + 64;
  float* __restrict__ omask = out + (size_t)U * CO;
  const float4* __restrict__ pdv = (const float4*)pd;

  // ---- prologue: load trip-0 pillar record (3 independent dwordx4 + cnt)
  int pcur = wave0 < U ? wave0 : (U - 1);
  float4 A = pdv[3 * pcur];      // vf0[0..3]
  float4 B = pdv[3 * pcur + 1];  // vf0[4], vf1[0..2]
  float4 C = pdv[3 * pcur + 2];  // vf1[3], vf1[4], bits(b0), bits(b1)
  int cnt = unq_cnt[pcur];

  for (int t = 0; t < trips; ++t) {
    const int p = wave0 + t * totalWaves;
    if (p >= U) break;               // wave-uniform

    // ---- prefetch next trip's record (independent loads, vmcnt domain)
    int pn = p + totalWaves;
    pn = pn < U ? pn : (U - 1);
    const float4 An = pdv[3 * pn];
    const float4 Bn = pdv[3 * pn + 1];
    const float4 Cn = pdv[3 * pn + 2];
    const int cntn  = unq_cnt[pn];

    const bool has2 = (cnt >= 2);
    const int b0  = __builtin_bit_cast(int, C.z) & 31;
    const int b1i = __builtin_bit_cast(int, C.w) & 31;

    // ---- up-dimension MLP layer 1 (lanes 0-31: voxel0, 32-63: voxel1)
    float h = b1r;
    h += (half ? B.y : A.x) * w1r[0];
    h += (half ? B.z : A.y) * w1r[1];
    h += (half ? B.w : A.z) * w1r[2];
    h += (half ? C.x : A.w) * w1r[3];
    h += (half ? C.y : B.x) * w1r[4];
    const float hr = fmaxf(h, 0.0f);

    // layer 2 via LDS broadcast reads, 2-way split accumulators
    hrb[lane] = hr;
    __builtin_amdgcn_wave_barrier();
    __builtin_amdgcn_s_waitcnt(0xC07F);   // lgkmcnt(0)
    __builtin_amdgcn_wave_barrier();
    const float4* h4 = (const float4*)hrb;
    float y0a = b2r, y0b = 0.0f, y1a = b2r, y1b = 0.0f;
#pragma unroll
    for (int k = 0; k < 4; ++k) {
      float4 a = h4[k];        // voxel0 hr, hidden 4k..4k+3 (broadcast)
      float4 b = h4[4 + k];    // voxel0 hr, hidden 16+4k..
      float4 c = h4[8 + k];    // voxel1 hr
      float4 d = h4[12 + k];
      y0a += a.x * w2r[4 * k]      + a.y * w2r[4 * k + 1] +
             a.z * w2r[4 * k + 2]  + a.w * w2r[4 * k + 3];
      y0b += b.x * w2r[16 + 4 * k]     + b.y * w2r[16 + 4 * k + 1] +
             b.z * w2r[16 + 4 * k + 2] + b.w * w2r[16 + 4 * k + 3];
      y1a += c.x * w2r[4 * k]      + c.y * w2r[4 * k + 1] +
             c.z * w2r[4 * k + 2]  + c.w * w2r[4 * k + 3];
      y1b += d.x * w2r[16 + 4 * k]     + d.y * w2r[16 + 4 * k + 1] +
             d.z * w2r[16 + 4 * k + 2] + d.w * w2r[16 + 4 * k + 3];
    }
    const float y0 = y0a + y0b;
    const float y1 = y1a + y1b;

    // ---- per-channel pooled stats over 32 bins (30 empty bins = c0)
    const float sumy = has2 ? (y0 + y1) : y0;
    const float maxy = has2 ? fmaxf(y0, y1) : y0;
    const float avg  = (c0 * (float)(NB - (has2 ? 2 : 1)) + sumy) *
                       (1.0f / (float)NB);
    const float mx   = fmaxf(maxy, c0);

    // ---- channel attention: sigmoid(mlp(avg) + mlp(max))
    plb[half * 36 + j32]      = avg;
    plb[72 + half * 36 + j32] = mx;
    __builtin_amdgcn_wave_barrier();
    __builtin_amdgcn_s_waitcnt(0xC07F);   // lgkmcnt(0)
    __builtin_amdgcn_wave_barrier();
    float ta = 0.0f, tb = 0.0f;
    const float4* r4 = (const float4*)(plb + pool * 72 + half * 36);
#pragma unroll
    for (int k = 0; k < 4; ++k) {
      float4 q = r4[k];
      float4 u = r4[4 + k];
      ta += q.x * wc1r[4 * k]      + q.y * wc1r[4 * k + 1] +
            q.z * wc1r[4 * k + 2]  + q.w * wc1r[4 * k + 3];
      tb += u.x * wc1r[16 + 4 * k]     + u.y * wc1r[16 + 4 * k + 1] +
            u.z * wc1r[16 + 4 * k + 2] + u.w * wc1r[16 + 4 * k + 3];
    }
    float tt = ta + tb;
    tt += __shfl_xor(tt, 32);                   // combine channel halves
    const float r = fmaxf(tt + bc1r, 0.0f);
    const float g = r + __shfl_xor(r, 16);      // relu(h_avg)+relu(h_max)
    // 4-way split of the readlane chain (was 16 serial FMA+readlane)
    float p0 = 2.0f * bc2r, p1 = 0.0f, p2 = 0.0f, p3 = 0.0f;
#pragma unroll
    for (int j = 0; j < 4; ++j) {
      p0 += frl(g, j)      * wc2r[j];
      p1 += frl(g, 4 + j)  * wc2r[4 + j];
      p2 += frl(g, 8 + j)  * wc2r[8 + j];
      p3 += frl(g, 12 + j) * wc2r[12 + j];
    }
    const float attc = sgm((p0 + p1) + (p2 + p3));

    // ---- bin-attention reductions via DPP (3 columns: c0, y0, y1)
    const float pc0 = attc * c0;
    const float py0 = attc * y0;
    const float py1 = attc * y1;
    const float aa = half ? py1 : py0;
    const float zx = __shfl_xor(half ? py0 : py1, 32);  // cross-half exch
    float vs = red32_sum(aa + zx);
    float vm = red32_max(fmaxf(aa, zx));
    const float sy0 = frl(vs, 31), sy1 = frl(vs, 63);
    const float my0 = frl(vm, 31), my1 = frl(vm, 63);
    const float sc  = frl(red64_sum(pc0), 63);
    const float mc  = frl(red64_max(pc0), 63);

    // ---- analytic conv (2-way split accumulation)
    const float inv64 = 1.0f / 64.0f;
    const float Mn = sc * inv64;
    const float Mx = mc;
    int k0 = b0 - j32 + 3;  k0 = ((unsigned)k0 <= 6u) ? k0 : 7;
    int k1 = b1i - j32 + 3; k1 = (has2 && (unsigned)k1 <= 6u) ? k1 : 7;
    const float2 w0 = wtab[k0];
    const float2 w1c = wtab[k1];
    const float accA = bspr + Mn * wsum_m + Mx * wsum_x;
    const float accB = ((sy0 - sc) * inv64) * w0.x + (my0 - mc) * w0.y +
                       ((sy1 - sc) * inv64) * w1c.x + (my1 - mc) * w1c.y;
    const float acc = accA + accB;

    // sigmoid only at the 4 points that matter (monotone => reduce acc)
    const bool occ = (j32 == b0) || (has2 && (j32 == b1i));
    const float macc =  frl(red32_max(occ ? -3.0e38f :  acc), 31);
    const float nacc = -frl(red32_max(occ ? -3.0e38f : -acc), 31);
    const float sig0 = sgm(frl(acc, b0));
    const float sig1 = sgm(frl(acc, b1i));
    const float sE = sgm(macc);   // max sigmoid over empty bins
    const float sI = sgm(nacc);   // min sigmoid over empty bins

    // ---- final max over bins of attc * x_b * sig_b  (attc > 0)
    float m = y0 * sig0;
    if (has2) m = fmaxf(m, y1 * sig1);
    const float eterm = (c0 >= 0.0f) ? (c0 * sE) : (c0 * sI);
    m = fmaxf(m, eterm);

    out[(size_t)p * CO + lane] = attc * m;
    if (lane == 0) omask[p] = has2 ? 1.0f : 0.0f;

    // ---- rotate pipeline registers
    A = An; B = Bn; C = Cn; cnt = cntn;
  }
}

extern "C" void kernel_launch(void* const* d_in, const int* in_sizes, int n_in,
                              void* d_out, int out_size, void* d_ws, size_t ws_size,
                              hipStream_t stream) {
  const float* vf      = (const float*)d_in[0];
  const int*   vcoord  = (const int*)d_in[1];
  // d_in[2] = unq_coords (unused: identity)
  const int*   unq_inv = (const int*)d_in[3];
  const int*   unq_cnt = (const int*)d_in[4];
  const float* W1  = (const float*)d_in[5];
  const float* b1  = (const float*)d_in[6];
  const float* W2  = (const float*)d_in[7];
  const float* b2  = (const float*)d_in[8];
  const float* Wc1 = (const float*)d_in[9];
  const float* bc1 = (const float*)d_in[10];
  const float* Wc2 = (const float*)d_in[11];
  const float* bc2 = (const float*)d_in[12];
  const float* Wsp = (const float*)d_in[13];
  const float* bsp = (const float*)d_in[14];

  const int N = in_sizes[3];   // voxels
  const int U = in_sizes[4];   // pillars

  float* pd = (float*)d_ws;    // 12 floats per pillar (4.8 MB @ U=100k)

  pack_kernel<<<(N + 255) / 256, 256, 0, stream>>>(vf, vcoord, unq_inv, pd, N);

  const int blocks = 2048;               // 8192 waves, grid-stride
  const int totalWaves = blocks * 4;
  const int trips = (U + totalWaves - 1) / totalWaves;
  cbam_kernel<<<blocks, 256, 0, stream>>>(
      pd, unq_cnt, W1, b1, W2, b2, Wc1, bc1, Wc2, bc2,
      Wsp, bsp, (float*)d_out, U, trips, totalWaves);
}